// Round 5
// baseline (344.604 us; speedup 1.0000x reference)
//
#include <hip/hip_runtime.h>
#include <hip/hip_bf16.h>

#define DM 1024
#define SEQ 2048
#define NBATCH 4

using f32x4 = __attribute__((ext_vector_type(4))) float;
using s16x8 = __attribute__((ext_vector_type(8))) short;   // 8 bf16 in 4 VGPRs
using u16x4 = __attribute__((ext_vector_type(4))) unsigned short;
using u16x8 = __attribute__((ext_vector_type(8))) unsigned short;

__device__ __forceinline__ unsigned short f2bf(float f) {
  union { float f; unsigned u; } v; v.f = f;
  return (unsigned short)((v.u + 0x7fffu + ((v.u >> 16) & 1u)) >> 16);  // RNE
}

// ---------------- conversion kernels ----------------

__global__ void cvt_x(const float* __restrict__ X, unsigned short* __restrict__ XB) {
  const int i = blockIdx.x * 256 + threadIdx.x;           // 8 elems/thread
  const f32x4* p = (const f32x4*)X;
  f32x4 a = p[2 * i], b = p[2 * i + 1];
  u16x8 o;
#pragma unroll
  for (int q = 0; q < 4; q++) { o[q] = f2bf(a[q]); o[4 + q] = f2bf(b[q]); }
  *(u16x8*)(XB + (size_t)i * 8) = o;
}

// WT[seg][n][k] = W_seg[k][n], bf16
__global__ void transpose_w(const float* __restrict__ Wq, const float* __restrict__ Wk,
                            const float* __restrict__ Wv, unsigned short* __restrict__ WT) {
  const int seg = blockIdx.z;
  const float* W = (seg == 0) ? Wq : (seg == 1) ? Wk : Wv;
  unsigned short* out = WT + (size_t)seg * DM * DM;
  __shared__ float t[32][33];
  const int k0 = blockIdx.y * 32, n0 = blockIdx.x * 32;
  const int tr = threadIdx.x >> 5, tc = threadIdx.x & 31;
#pragma unroll
  for (int p = 0; p < 4; p++) {
    int r = tr + p * 8;
    t[r][tc] = W[(size_t)(k0 + r) * DM + n0 + tc];
  }
  __syncthreads();
#pragma unroll
  for (int p = 0; p < 4; p++) {
    int r = tr + p * 8;
    out[(size_t)(n0 + r) * DM + k0 + tc] = f2bf(t[tc][r]);
  }
}

// softmax-combine: per (batch,row) fold 16 tile stats (m,s) into scale table
// T[row][0..16]: T[0]=1, T[t]=exp(m_{t-1}-m_t), T[16]=exp(m_15-M)/L.
__global__ void combine_k(const float* __restrict__ ms, const float* __restrict__ ss,
                          float* __restrict__ T) {
  const int idx = blockIdx.x * 256 + threadIdx.x;     // 0..8191 = b*2048+row
  const float* m = ms + (size_t)idx * 16;
  const float* s = ss + (size_t)idx * 16;
  float mv[16];
#pragma unroll
  for (int t = 0; t < 16; t++) mv[t] = m[t];
  float M = mv[0];
#pragma unroll
  for (int t = 1; t < 16; t++) M = fmaxf(M, mv[t]);
  float L = 0.f;
#pragma unroll
  for (int t = 0; t < 16; t++) L += s[t] * __expf(mv[t] - M);
  float* o = T + (size_t)idx * 17;
  o[0] = 1.0f;
#pragma unroll
  for (int t = 1; t < 16; t++) o[t] = __expf(mv[t - 1] - mv[t]);
  o[16] = __expf(mv[15] - M) / L;
}

// ---------------- bf16 NT GEMM: 128x128 tile, BK=64, reg-staged pipeline ----------------
// K-loop (round-4 proven): buffer_load->VGPR (no vmcnt drain at barriers) ->
// MFMA tile k from LDS -> raw s_barrier (lgkm only) -> ds_write tile k+1
// (vmcnt wait lands here, after a full compute phase of cover) -> barrier.
// XOR swizzle key=row&7: conflict-free ds_write/read_b128.
// MODE 0: QKV  (C0=Q bf16, C1=K bf16, C2=V^T bf16, biases)
// MODE 1: S-gemm + split-softmax epilogue: writes P'=bf16(exp(s-m_tile)) to C0,
//         per-(row,tile) stats to sm/sv.  per-batch via blockIdx.z
// MODE 2: O = sum_t T-rescaled P'_t Vt_t, fp32 (C0), per-batch; Tt = scale table
template <int MODE, int LDA, int LDB, int KDIM>
__global__ void gemm_nt(const unsigned short* __restrict__ A,
                        const unsigned short* __restrict__ B,
                        void* __restrict__ C0,
                        unsigned short* __restrict__ C1,
                        unsigned short* __restrict__ C2,
                        const float* __restrict__ bq,
                        const float* __restrict__ bk,
                        const float* __restrict__ bv,
                        float* __restrict__ sm,
                        float* __restrict__ sv,
                        const float* __restrict__ Tt) {
  __shared__ unsigned short lA[128 * 64];   // 16 KB
  __shared__ unsigned short lB[128 * 64];   // 16 KB

  const int tid = threadIdx.x;
  const int w = tid >> 6;
  const int L = tid & 63;
  const int wm = w & 1, wn = w >> 1;
  const int qd = L >> 4, ll = L & 15;
  const int bz = blockIdx.z;
  const int tileM = blockIdx.y * 128, tileN = blockIdx.x * 128;

  const unsigned short* Ab = A;
  const unsigned short* Bb = B;
  if (MODE == 1) { Ab += (size_t)bz * SEQ * DM; Bb += (size_t)bz * SEQ * DM; }
  if (MODE == 2) { Ab += (size_t)bz * SEQ * SEQ; Bb += (size_t)bz * DM * SEQ; }

  // staging geometry: thread t -> row srow=t>>3 (0..31, +32*i), phys chunk t&7,
  // global chunk = (t&7) ^ (row&7).
  const int srow = tid >> 3;
  const int pch = tid & 7;
  const int gch = pch ^ (srow & 7);
  const unsigned short* gA = Ab + (size_t)(tileM + srow) * LDA + gch * 8;
  const unsigned short* gB = Bb + (size_t)(tileN + srow) * LDB + gch * 8;
  unsigned short* wA = &lA[srow * 64 + pch * 8];
  unsigned short* wB = &lB[srow * 64 + pch * 8];

  u16x8 rA[4], rB[4];
#define LOADT(kt) do {                                                         \
    const size_t kk_ = (size_t)(kt) * 64;                                      \
    _Pragma("unroll")                                                          \
    for (int i_ = 0; i_ < 4; i_++) {                                           \
      rA[i_] = *(const u16x8*)(gA + (size_t)i_ * 32 * LDA + kk_);              \
      rB[i_] = *(const u16x8*)(gB + (size_t)i_ * 32 * LDB + kk_);              \
    }                                                                          \
  } while (0)
#define WRITET() do {                                                          \
    _Pragma("unroll")                                                          \
    for (int i_ = 0; i_ < 4; i_++) {                                           \
      *(u16x8*)(wA + i_ * 32 * 64) = rA[i_];                                   \
      *(u16x8*)(wB + i_ * 32 * 64) = rB[i_];                                   \
    }                                                                          \
  } while (0)

  f32x4 acc[4][4];
#pragma unroll
  for (int i = 0; i < 4; i++)
#pragma unroll
    for (int j = 0; j < 4; j++) acc[i][j] = (f32x4){0.f, 0.f, 0.f, 0.f};

  const int sw = L & 7;         // swizzle key for fragment rows

  // MODE2: prefetched scale-table values, one per (i,r) acc row
  float tTn[4][4];
  const float* Tp = nullptr;
  if (MODE == 2) {
    Tp = Tt + ((size_t)bz * SEQ + tileM + wm * 64) * 17;
#pragma unroll
    for (int i = 0; i < 4; i++)
#pragma unroll
      for (int r = 0; r < 4; r++) tTn[i][r] = Tp[(i * 16 + qd * 4 + r) * 17 + 1];
  }

  constexpr int NK = KDIM / 64;
  LOADT(0);
  WRITET();                      // vmcnt wait inserted before these writes
  __syncthreads();

  for (int k = 0; k < NK; ++k) {
    if (MODE == 2 && k >= 2 && (k & 1) == 0) {
      // tile boundary t=k/2: rescale acc by T[row][t] (held in tTn), then
      // prefetch T[row][t+1] (plain global loads -> no barrier drain).
#pragma unroll
      for (int i = 0; i < 4; i++)
#pragma unroll
        for (int j = 0; j < 4; j++)
#pragma unroll
          for (int r = 0; r < 4; r++) acc[i][j][r] *= tTn[i][r];
      const int tn = (k >> 1) + 1;
#pragma unroll
      for (int i = 0; i < 4; i++)
#pragma unroll
        for (int r = 0; r < 4; r++) tTn[i][r] = Tp[(i * 16 + qd * 4 + r) * 17 + tn];
    }

    if (k + 1 < NK) LOADT(k + 1);     // global->VGPR, flies across compute

#pragma unroll
    for (int s = 0; s < 2; s++) {     // two K=32 halves of the BK=64 tile
      const int pc = ((s * 4 + qd) ^ sw) * 8;
      s16x8 av[4], bv4[4];
#pragma unroll
      for (int i = 0; i < 4; i++)
        av[i] = *(const s16x8*)&lA[(wm * 64 + i * 16 + ll) * 64 + pc];
#pragma unroll
      for (int j = 0; j < 4; j++)
        bv4[j] = *(const s16x8*)&lB[(wn * 64 + j * 16 + ll) * 64 + pc];
#pragma unroll
      for (int i = 0; i < 4; i++)
#pragma unroll
        for (int j = 0; j < 4; j++)
          acc[i][j] = __builtin_amdgcn_mfma_f32_16x16x32_bf16(av[i], bv4[j], acc[i][j], 0, 0, 0);
    }

    if (k + 1 < NK) {
      __builtin_amdgcn_s_waitcnt(0xC07F);       // lgkmcnt(0) only; vmem in flight
      __builtin_amdgcn_sched_barrier(0);
      __builtin_amdgcn_s_barrier();
      __builtin_amdgcn_sched_barrier(0);
      WRITET();                                  // vmcnt wait auto-inserted here
      __syncthreads();
    }
  }
#undef LOADT
#undef WRITET

  // ---------------- epilogues ----------------
  // C/D layout: col = wn*64 + j*16 + ll ; row = wm*64 + i*16 + qd*4 + r
  if (MODE == 0) {
#pragma unroll
    for (int i = 0; i < 4; i++) {
      const int gm0 = tileM + wm * 64 + i * 16 + qd * 4;
#pragma unroll
      for (int j = 0; j < 4; j++) {
        const int gn = tileN + wn * 64 + j * 16 + ll;
        const int seg = gn >> 10;          // block-uniform
        const int colin = gn & 1023;
        if (seg == 0) {
          const float bias = bq[colin];
          unsigned short* Q = (unsigned short*)C0;
#pragma unroll
          for (int r = 0; r < 4; r++) Q[(size_t)(gm0 + r) * DM + colin] = f2bf(acc[i][j][r] + bias);
        } else if (seg == 1) {
          const float bias = bk[colin];
#pragma unroll
          for (int r = 0; r < 4; r++) C1[(size_t)(gm0 + r) * DM + colin] = f2bf(acc[i][j][r] + bias);
        } else {                            // V, stored transposed: Vt[b][d][s]
          const float bias = bv[colin];
          u16x4 pk;
#pragma unroll
          for (int r = 0; r < 4; r++) pk[r] = f2bf(acc[i][j][r] + bias);
          const int b = gm0 >> 11, s0 = gm0 & 2047;
          *(u16x4*)(C2 + ((size_t)((b << 10) + colin)) * SEQ + s0) = pk;
        }
      }
    }
  } else if (MODE == 1) {
    // scale scores by 1/32
#pragma unroll
    for (int i = 0; i < 4; i++)
#pragma unroll
      for (int j = 0; j < 4; j++)
#pragma unroll
        for (int r = 0; r < 4; r++) acc[i][j][r] *= 0.03125f;

    __syncthreads();                       // all waves done with lA reads
    float* pmx = (float*)lA;               // [2][128] per-wn row maxes
    float* psm = (float*)lA + 256;         // [2][128] per-wn row sums

    // per-wave (64-col) row max: reduce over j then over the 16-lane group
    float wmax[4][4];
#pragma unroll
    for (int i = 0; i < 4; i++)
#pragma unroll
      for (int r = 0; r < 4; r++) {
        float v = fmaxf(fmaxf(acc[i][0][r], acc[i][1][r]), fmaxf(acc[i][2][r], acc[i][3][r]));
#pragma unroll
        for (int m = 1; m < 16; m <<= 1) v = fmaxf(v, __shfl_xor(v, m, 16));
        wmax[i][r] = v;
      }
    if (ll == 0) {
#pragma unroll
      for (int i = 0; i < 4; i++)
#pragma unroll
        for (int r = 0; r < 4; r++)
          pmx[wn * 128 + wm * 64 + i * 16 + qd * 4 + r] = wmax[i][r];
    }
    __syncthreads();
    float mt[4][4];
#pragma unroll
    for (int i = 0; i < 4; i++)
#pragma unroll
      for (int r = 0; r < 4; r++) {
        const int row = wm * 64 + i * 16 + qd * 4 + r;
        mt[i][r] = fmaxf(pmx[row], pmx[128 + row]);
      }
    // exp in place (exact fp32), per-wave row sums
    float wsum[4][4];
#pragma unroll
    for (int i = 0; i < 4; i++)
#pragma unroll
      for (int r = 0; r < 4; r++) {
        float s = 0.f;
#pragma unroll
        for (int j = 0; j < 4; j++) {
          float e = __expf(acc[i][j][r] - mt[i][r]);
          acc[i][j][r] = e;
          s += e;
        }
#pragma unroll
        for (int m = 1; m < 16; m <<= 1) s += __shfl_xor(s, m, 16);
        wsum[i][r] = s;
      }
    if (ll == 0) {
#pragma unroll
      for (int i = 0; i < 4; i++)
#pragma unroll
        for (int r = 0; r < 4; r++)
          psm[wn * 128 + wm * 64 + i * 16 + qd * 4 + r] = wsum[i][r];
    }
    __syncthreads();
    if (wn == 0 && ll == 0) {              // 8 writer threads cover 128 rows
#pragma unroll
      for (int i = 0; i < 4; i++)
#pragma unroll
        for (int r = 0; r < 4; r++) {
          const int row = wm * 64 + i * 16 + qd * 4 + r;
          const size_t sidx = ((size_t)bz * SEQ + tileM + row) * 16 + blockIdx.x;
          sm[sidx] = mt[i][r];
          sv[sidx] = psm[row] + psm[128 + row];
        }
    }
    // store P' bf16: row fixed per (i,r); cols j*16+ll
    unsigned short* P = (unsigned short*)C0 + (size_t)bz * SEQ * SEQ;
#pragma unroll
    for (int i = 0; i < 4; i++)
#pragma unroll
      for (int r = 0; r < 4; r++) {
        const int row_g = tileM + wm * 64 + i * 16 + qd * 4 + r;
        unsigned short* dst = P + (size_t)row_g * SEQ + tileN + wn * 64 + ll;
#pragma unroll
        for (int j = 0; j < 4; j++) dst[j * 16] = f2bf(acc[i][j][r]);
      }
  } else {
    // final scale T[row][16] (in tTn), then store fp32
    float* O = (float*)C0 + (size_t)bz * SEQ * DM;
#pragma unroll
    for (int i = 0; i < 4; i++) {
      const int gm0 = tileM + wm * 64 + i * 16 + qd * 4;
#pragma unroll
      for (int j = 0; j < 4; j++) {
        const int gn = tileN + wn * 64 + j * 16 + ll;
#pragma unroll
        for (int r = 0; r < 4; r++)
          O[(size_t)(gm0 + r) * DM + gn] = acc[i][j][r] * tTn[i][r];
      }
    }
  }
}

// ---------------- launch ----------------
// ws layout (bytes):
//   xb  @ 0         : 16 MB   bf16 x       [8192,1024]
//   wt  @ 16777216  :  6 MB   bf16 W^T     [3072,1024]
//   qb  @ 23068672  : 16 MB   bf16 Q       [8192,1024]
//   kb  @ 39845888  : 16 MB   bf16 K       [8192,1024]
//   vt  @ 56623104  : 16 MB   bf16 V^T     [4][1024][2048]
//   P   @ 73400320  : 32 MB   bf16 P'      [4][2048][2048]
//   ms  @ 106954752 : 512 KB  fp32 stats m [4][2048][16]
//   ss  @ 107479040 : 512 KB  fp32 stats s [4][2048][16]
//   T   @ 108003328 : 544 KB  fp32 scale   [4][2048][17]
// total ~108.5 MB
extern "C" void kernel_launch(void* const* d_in, const int* in_sizes, int n_in,
                              void* d_out, int out_size, void* d_ws, size_t ws_size,
                              hipStream_t stream) {
  (void)in_sizes; (void)n_in; (void)out_size; (void)ws_size;
  const float* x  = (const float*)d_in[0];
  const float* Wq = (const float*)d_in[1];
  const float* bq = (const float*)d_in[2];
  const float* Wk = (const float*)d_in[3];
  const float* bk = (const float*)d_in[4];
  const float* Wv = (const float*)d_in[5];
  const float* bv = (const float*)d_in[6];
  float* out = (float*)d_out;
  char* ws = (char*)d_ws;
  unsigned short* xb = (unsigned short*)(ws + 0);
  unsigned short* wt = (unsigned short*)(ws + 16777216);
  unsigned short* qb = (unsigned short*)(ws + 23068672);
  unsigned short* kb = (unsigned short*)(ws + 39845888);
  unsigned short* vt = (unsigned short*)(ws + 56623104);
  unsigned short* P  = (unsigned short*)(ws + 73400320);
  float*          ms = (float*)(ws + 106954752);
  float*          ss = (float*)(ws + 107479040);
  float*          Tt = (float*)(ws + 108003328);

  cvt_x<<<4096, 256, 0, stream>>>(x, xb);
  transpose_w<<<dim3(32, 32, 3), 256, 0, stream>>>(Wq, Wk, Wv, wt);
  gemm_nt<0, 1024, 1024, 1024><<<dim3(24, 64, 1), 256, 0, stream>>>(
      xb, wt, (void*)qb, kb, vt, bq, bk, bv, nullptr, nullptr, nullptr);
  gemm_nt<1, 1024, 1024, 1024><<<dim3(16, 16, 4), 256, 0, stream>>>(
      qb, kb, (void*)P, nullptr, nullptr, nullptr, nullptr, nullptr, ms, ss, nullptr);
  combine_k<<<32, 256, 0, stream>>>(ms, ss, Tt);
  gemm_nt<2, 2048, 2048, 2048><<<dim3(8, 16, 4), 256, 0, stream>>>(
      P, vt, (void*)out, nullptr, nullptr, nullptr, nullptr, nullptr, nullptr, nullptr, Tt);
}

// Round 6
// 276.274 us; speedup vs baseline: 1.2473x; 1.2473x over previous
//
#include <hip/hip_runtime.h>
#include <hip/hip_bf16.h>

#define DM 1024
#define SEQ 2048
#define NBATCH 4

using f32x4 = __attribute__((ext_vector_type(4))) float;
using s16x8 = __attribute__((ext_vector_type(8))) short;   // 8 bf16 in 4 VGPRs
using u16x4 = __attribute__((ext_vector_type(4))) unsigned short;
using u16x8 = __attribute__((ext_vector_type(8))) unsigned short;

__device__ __forceinline__ unsigned short f2bf(float f) {
  union { float f; unsigned u; } v; v.f = f;
  return (unsigned short)((v.u + 0x7fffu + ((v.u >> 16) & 1u)) >> 16);  // RNE
}

// ---------------- fused prep: x->bf16 cast  +  W transpose/cast ----------------
// blocks [0,4096): cvt 8 elems/thread of x.  blocks [4096,7168): 32x32 W tiles.
__global__ void prep_k(const float* __restrict__ X,
                       const float* __restrict__ Wq, const float* __restrict__ Wk,
                       const float* __restrict__ Wv,
                       unsigned short* __restrict__ XB, unsigned short* __restrict__ WT) {
  __shared__ float t[32][33];
  const int b = blockIdx.x;
  if (b < 4096) {
    const int i = b * 256 + threadIdx.x;
    const f32x4* p = (const f32x4*)X;
    f32x4 a = p[2 * i], c = p[2 * i + 1];
    u16x8 o;
#pragma unroll
    for (int q = 0; q < 4; q++) { o[q] = f2bf(a[q]); o[4 + q] = f2bf(c[q]); }
    *(u16x8*)(XB + (size_t)i * 8) = o;
  } else {
    const int r2 = b - 4096;
    const int seg = r2 >> 10;
    const int rem = r2 & 1023;
    const int k0 = (rem >> 5) * 32, n0 = (rem & 31) * 32;
    const float* W = (seg == 0) ? Wq : (seg == 1) ? Wk : Wv;
    unsigned short* out = WT + (size_t)seg * DM * DM;
    const int tr = threadIdx.x >> 5, tc = threadIdx.x & 31;
#pragma unroll
    for (int p = 0; p < 4; p++) {
      int r = tr + p * 8;
      t[r][tc] = W[(size_t)(k0 + r) * DM + n0 + tc];
    }
    __syncthreads();
#pragma unroll
    for (int p = 0; p < 4; p++) {
      int r = tr + p * 8;
      out[(size_t)(n0 + r) * DM + k0 + tc] = f2bf(t[tc][r]);
    }
  }
}

// softmax-combine: per (batch,row) fold 16 tile stats (m,s) into scale table,
// TRANSPOSED layout T[t][b*2048+row], t=0..16:
// T[0]=1, T[t]=exp(m_{t-1}-m_t), T[16]=exp(m_15-M)/L.
__global__ void combine_k(const float* __restrict__ ms, const float* __restrict__ ss,
                          float* __restrict__ T) {
  const int idx = blockIdx.x * 256 + threadIdx.x;     // 0..8191
  const float* m = ms + (size_t)idx * 16;
  const float* s = ss + (size_t)idx * 16;
  float mv[16];
#pragma unroll
  for (int t = 0; t < 16; t++) mv[t] = m[t];
  float M = mv[0];
#pragma unroll
  for (int t = 1; t < 16; t++) M = fmaxf(M, mv[t]);
  float L = 0.f;
#pragma unroll
  for (int t = 0; t < 16; t++) L += s[t] * __expf(mv[t] - M);
  T[idx] = 1.0f;
#pragma unroll
  for (int t = 1; t < 16; t++) T[t * 8192 + idx] = __expf(mv[t - 1] - mv[t]);
  T[16 * 8192 + idx] = __expf(mv[15] - M) / L;
}

// ---------------- bf16 NT GEMM: 128x128 tile, BK=64, reg-staged pipeline ----------------
// K-loop (round-4 proven): buffer_load->VGPR (no vmcnt drain at barriers) ->
// MFMA tile k from LDS -> raw s_barrier (lgkm only) -> ds_write tile k+1
// (vmcnt wait lands after a full compute phase of cover) -> barrier.
// XOR swizzle key=row&7: conflict-free ds_write/read_b128.
// MODE 0: QKV  (C0=Q bf16, C1=K bf16, C2=V^T bf16, biases)
// MODE 1: S-gemm + split-softmax epilogue: P'=bf16(exp(s-m_tile)) via LDS
//         transpose -> coalesced u16x8 stores; per-(row,tile) stats to sm/sv.
// MODE 2: O = telescoped sum_t P'_t Vt_t, fp32; Tt = scale table [17][8192]
template <int MODE, int LDA, int LDB, int KDIM>
__global__ void gemm_nt(const unsigned short* __restrict__ A,
                        const unsigned short* __restrict__ B,
                        void* __restrict__ C0,
                        unsigned short* __restrict__ C1,
                        unsigned short* __restrict__ C2,
                        const float* __restrict__ bq,
                        const float* __restrict__ bk,
                        const float* __restrict__ bv,
                        float* __restrict__ sm,
                        float* __restrict__ sv,
                        const float* __restrict__ Tt) {
  __shared__ unsigned short lbuf[16384];    // 32 KB: lA=[0,8192), lB=[8192,16384)
  __shared__ float redm[256], reds[256];    // MODE1 stats scratch (2 KB)
  unsigned short* lA = lbuf;
  unsigned short* lB = lbuf + 8192;

  const int tid = threadIdx.x;
  const int w = tid >> 6;
  const int L = tid & 63;
  const int wm = w & 1, wn = w >> 1;
  const int qd = L >> 4, ll = L & 15;
  const int bz = blockIdx.z;
  const int tileM = blockIdx.y * 128, tileN = blockIdx.x * 128;

  const unsigned short* Ab = A;
  const unsigned short* Bb = B;
  if (MODE == 1) { Ab += (size_t)bz * SEQ * DM; Bb += (size_t)bz * SEQ * DM; }
  if (MODE == 2) { Ab += (size_t)bz * SEQ * SEQ; Bb += (size_t)bz * DM * SEQ; }

  // staging geometry: thread t -> row srow=t>>3 (0..31, +32*i), phys chunk t&7,
  // global chunk = (t&7) ^ (row&7).
  const int srow = tid >> 3;
  const int pch = tid & 7;
  const int gch = pch ^ (srow & 7);
  const unsigned short* gA = Ab + (size_t)(tileM + srow) * LDA + gch * 8;
  const unsigned short* gB = Bb + (size_t)(tileN + srow) * LDB + gch * 8;
  unsigned short* wA = &lA[srow * 64 + pch * 8];
  unsigned short* wB = &lB[srow * 64 + pch * 8];

  u16x8 rA[4], rB[4];
#define LOADT(kt) do {                                                         \
    const size_t kk_ = (size_t)(kt) * 64;                                      \
    _Pragma("unroll")                                                          \
    for (int i_ = 0; i_ < 4; i_++) {                                           \
      rA[i_] = *(const u16x8*)(gA + (size_t)i_ * 32 * LDA + kk_);              \
      rB[i_] = *(const u16x8*)(gB + (size_t)i_ * 32 * LDB + kk_);              \
    }                                                                          \
  } while (0)
#define WRITET() do {                                                          \
    _Pragma("unroll")                                                          \
    for (int i_ = 0; i_ < 4; i_++) {                                           \
      *(u16x8*)(wA + i_ * 32 * 64) = rA[i_];                                   \
      *(u16x8*)(wB + i_ * 32 * 64) = rB[i_];                                   \
    }                                                                          \
  } while (0)

  f32x4 acc[4][4];
#pragma unroll
  for (int i = 0; i < 4; i++)
#pragma unroll
    for (int j = 0; j < 4; j++) acc[i][j] = (f32x4){0.f, 0.f, 0.f, 0.f};

  const int sw = L & 7;         // swizzle key for fragment rows

  // MODE2: prefetched scale-table values (broadcast-coalesced layout)
  float tTn[4][4];
  const float* Tb = nullptr;
  if (MODE == 2) {
    Tb = Tt + (size_t)bz * SEQ + tileM + wm * 64;
#pragma unroll
    for (int i = 0; i < 4; i++)
#pragma unroll
      for (int r = 0; r < 4; r++) tTn[i][r] = Tb[1 * 8192 + i * 16 + qd * 4 + r];
  }

  constexpr int NK = KDIM / 64;
  LOADT(0);
  WRITET();                      // vmcnt wait inserted before these writes
  __syncthreads();

  for (int k = 0; k < NK; ++k) {
    if (MODE == 2 && k >= 2 && (k & 1) == 0) {
      // tile boundary t=k/2: rescale acc by T[t] (in tTn), prefetch T[t+1]
#pragma unroll
      for (int i = 0; i < 4; i++)
#pragma unroll
        for (int j = 0; j < 4; j++)
#pragma unroll
          for (int r = 0; r < 4; r++) acc[i][j][r] *= tTn[i][r];
      const int tn = (k >> 1) + 1;
#pragma unroll
      for (int i = 0; i < 4; i++)
#pragma unroll
        for (int r = 0; r < 4; r++) tTn[i][r] = Tb[(size_t)tn * 8192 + i * 16 + qd * 4 + r];
    }

    if (k + 1 < NK) LOADT(k + 1);     // global->VGPR, flies across compute

#pragma unroll
    for (int s = 0; s < 2; s++) {     // two K=32 halves of the BK=64 tile
      const int pc = ((s * 4 + qd) ^ sw) * 8;
      s16x8 av[4], bv4[4];
#pragma unroll
      for (int i = 0; i < 4; i++)
        av[i] = *(const s16x8*)&lA[(wm * 64 + i * 16 + ll) * 64 + pc];
#pragma unroll
      for (int j = 0; j < 4; j++)
        bv4[j] = *(const s16x8*)&lB[(wn * 64 + j * 16 + ll) * 64 + pc];
#pragma unroll
      for (int i = 0; i < 4; i++)
#pragma unroll
        for (int j = 0; j < 4; j++)
          acc[i][j] = __builtin_amdgcn_mfma_f32_16x16x32_bf16(av[i], bv4[j], acc[i][j], 0, 0, 0);
    }

    if (k + 1 < NK) {
      __builtin_amdgcn_s_waitcnt(0xC07F);       // lgkmcnt(0) only; vmem in flight
      __builtin_amdgcn_sched_barrier(0);
      __builtin_amdgcn_s_barrier();
      __builtin_amdgcn_sched_barrier(0);
      WRITET();                                  // vmcnt wait auto-inserted here
      __syncthreads();
    }
  }
#undef LOADT
#undef WRITET

  // ---------------- epilogues ----------------
  // C/D layout: col = wn*64 + j*16 + ll ; row = wm*64 + i*16 + qd*4 + r (local)
  if (MODE == 0) {
#pragma unroll
    for (int i = 0; i < 4; i++) {
      const int gm0 = tileM + wm * 64 + i * 16 + qd * 4;
#pragma unroll
      for (int j = 0; j < 4; j++) {
        const int gn = tileN + wn * 64 + j * 16 + ll;
        const int seg = gn >> 10;          // block-uniform
        const int colin = gn & 1023;
        if (seg == 0) {
          const float bias = bq[colin];
          unsigned short* Q = (unsigned short*)C0;
#pragma unroll
          for (int r = 0; r < 4; r++) Q[(size_t)(gm0 + r) * DM + colin] = f2bf(acc[i][j][r] + bias);
        } else if (seg == 1) {
          const float bias = bk[colin];
#pragma unroll
          for (int r = 0; r < 4; r++) C1[(size_t)(gm0 + r) * DM + colin] = f2bf(acc[i][j][r] + bias);
        } else {                            // V, stored transposed: Vt[b][d][s]
          const float bias = bv[colin];
          u16x4 pk;
#pragma unroll
          for (int r = 0; r < 4; r++) pk[r] = f2bf(acc[i][j][r] + bias);
          const int b = gm0 >> 11, s0 = gm0 & 2047;
          *(u16x4*)(C2 + ((size_t)((b << 10) + colin)) * SEQ + s0) = pk;
        }
      }
    }
  } else if (MODE == 1) {
    __syncthreads();                       // all waves done with K-loop LDS
    // scale scores by 1/32; per-wave row max (registers + shfl only)
    float mt[4][4];
#pragma unroll
    for (int i = 0; i < 4; i++)
#pragma unroll
      for (int r = 0; r < 4; r++) {
#pragma unroll
        for (int j = 0; j < 4; j++) acc[i][j][r] *= 0.03125f;
        float v = fmaxf(fmaxf(acc[i][0][r], acc[i][1][r]), fmaxf(acc[i][2][r], acc[i][3][r]));
#pragma unroll
        for (int m = 1; m < 16; m <<= 1) v = fmaxf(v, __shfl_xor(v, m, 16));
        mt[i][r] = v;
      }
    if (ll == 0) {
#pragma unroll
      for (int i = 0; i < 4; i++)
#pragma unroll
        for (int r = 0; r < 4; r++)
          redm[wn * 128 + wm * 64 + i * 16 + qd * 4 + r] = mt[i][r];
    }
    __syncthreads();
#pragma unroll
    for (int i = 0; i < 4; i++)
#pragma unroll
      for (int r = 0; r < 4; r++) {
        const int row = wm * 64 + i * 16 + qd * 4 + r;
        mt[i][r] = fmaxf(redm[row], redm[128 + row]);
      }
    // exp in place; per-wave row sums; write P' bf16 into lbuf (swizzled)
#pragma unroll
    for (int i = 0; i < 4; i++)
#pragma unroll
      for (int r = 0; r < 4; r++) {
        const int row = wm * 64 + i * 16 + qd * 4 + r;
        float s = 0.f;
#pragma unroll
        for (int j = 0; j < 4; j++) {
          float e = __expf(acc[i][j][r] - mt[i][r]);
          s += e;
          const int col = wn * 64 + j * 16 + ll;
          lbuf[row * 128 + ((((col >> 4) ^ (row & 7)) << 4) | (col & 15))] = f2bf(e);
        }
#pragma unroll
        for (int m = 1; m < 16; m <<= 1) s += __shfl_xor(s, m, 16);
        if (ll == 0) reds[wn * 128 + row] = s;
      }
    __syncthreads();                       // lbuf + reds complete
    if (wn == 0 && ll == 0) {              // 8 threads cover 128 rows
#pragma unroll
      for (int i = 0; i < 4; i++)
#pragma unroll
        for (int r = 0; r < 4; r++) {
          const int row = wm * 64 + i * 16 + qd * 4 + r;
          const size_t sidx = ((size_t)bz * SEQ + tileM + row) * 16 + blockIdx.x;
          sm[sidx] = mt[i][r];
          sv[sidx] = reds[row] + reds[128 + row];
        }
    }
    // coalesced P' store: 8 x u16x8 per thread
    unsigned short* P = (unsigned short*)C0 + (size_t)bz * SEQ * SEQ;
#pragma unroll
    for (int p = 0; p < 8; p++) {
      const int c = p * 256 + tid;
      const int row = c >> 4, cg = c & 15;
      const int phys = ((((cg >> 1) ^ (row & 7)) << 4) | ((cg & 1) << 3));
      u16x8 val = *(const u16x8*)&lbuf[row * 128 + phys];
      *(u16x8*)(P + (size_t)(tileM + row) * SEQ + tileN + cg * 8) = val;
    }
  } else {
    // final scale T[16] (in tTn), store fp32
    float* O = (float*)C0 + (size_t)bz * SEQ * DM;
#pragma unroll
    for (int i = 0; i < 4; i++) {
      const int gm0 = tileM + wm * 64 + i * 16 + qd * 4;
#pragma unroll
      for (int j = 0; j < 4; j++) {
        const int gn = tileN + wn * 64 + j * 16 + ll;
#pragma unroll
        for (int r = 0; r < 4; r++)
          O[(size_t)(gm0 + r) * DM + gn] = acc[i][j][r] * tTn[i][r];
      }
    }
  }
}

// ---------------- launch ----------------
// ws layout (bytes):
//   xb  @ 0         : 16 MB   bf16 x       [8192,1024]
//   wt  @ 16777216  :  6 MB   bf16 W^T     [3072,1024]
//   qb  @ 23068672  : 16 MB   bf16 Q       [8192,1024]
//   kb  @ 39845888  : 16 MB   bf16 K       [8192,1024]
//   vt  @ 56623104  : 16 MB   bf16 V^T     [4][1024][2048]
//   P   @ 73400320  : 32 MB   bf16 P'      [4][2048][2048]
//   ms  @ 106954752 : 512 KB  fp32 stats m [4][2048][16]
//   ss  @ 107479040 : 512 KB  fp32 stats s [4][2048][16]
//   T   @ 108003328 : 544 KB  fp32 scale   [17][4*2048]  (transposed)
// total ~108.5 MB
extern "C" void kernel_launch(void* const* d_in, const int* in_sizes, int n_in,
                              void* d_out, int out_size, void* d_ws, size_t ws_size,
                              hipStream_t stream) {
  (void)in_sizes; (void)n_in; (void)out_size; (void)ws_size;
  const float* x  = (const float*)d_in[0];
  const float* Wq = (const float*)d_in[1];
  const float* bq = (const float*)d_in[2];
  const float* Wk = (const float*)d_in[3];
  const float* bk = (const float*)d_in[4];
  const float* Wv = (const float*)d_in[5];
  const float* bv = (const float*)d_in[6];
  float* out = (float*)d_out;
  char* ws = (char*)d_ws;
  unsigned short* xb = (unsigned short*)(ws + 0);
  unsigned short* wt = (unsigned short*)(ws + 16777216);
  unsigned short* qb = (unsigned short*)(ws + 23068672);
  unsigned short* kb = (unsigned short*)(ws + 39845888);
  unsigned short* vt = (unsigned short*)(ws + 56623104);
  unsigned short* P  = (unsigned short*)(ws + 73400320);
  float*          ms = (float*)(ws + 106954752);
  float*          ss = (float*)(ws + 107479040);
  float*          Tt = (float*)(ws + 108003328);

  prep_k<<<7168, 256, 0, stream>>>(x, Wq, Wk, Wv, xb, wt);
  gemm_nt<0, 1024, 1024, 1024><<<dim3(24, 64, 1), 256, 0, stream>>>(
      xb, wt, (void*)qb, kb, vt, bq, bk, bv, nullptr, nullptr, nullptr);
  gemm_nt<1, 1024, 1024, 1024><<<dim3(16, 16, 4), 256, 0, stream>>>(
      qb, kb, (void*)P, nullptr, nullptr, nullptr, nullptr, nullptr, ms, ss, nullptr);
  combine_k<<<32, 256, 0, stream>>>(ms, ss, Tt);
  gemm_nt<2, 2048, 2048, 2048><<<dim3(8, 16, 4), 256, 0, stream>>>(
      P, vt, (void*)out, nullptr, nullptr, nullptr, nullptr, nullptr, nullptr, nullptr, Tt);
}

// Round 7
// 273.088 us; speedup vs baseline: 1.2619x; 1.0117x over previous
//
#include <hip/hip_runtime.h>
#include <hip/hip_bf16.h>

#define DM 1024
#define SEQ 2048
#define NBATCH 4

using f32x4 = __attribute__((ext_vector_type(4))) float;
using s16x8 = __attribute__((ext_vector_type(8))) short;   // 8 bf16 in 4 VGPRs
using u16x4 = __attribute__((ext_vector_type(4))) unsigned short;
using u16x8 = __attribute__((ext_vector_type(8))) unsigned short;

__device__ __forceinline__ unsigned short f2bf(float f) {
  union { float f; unsigned u; } v; v.f = f;
  return (unsigned short)((v.u + 0x7fffu + ((v.u >> 16) & 1u)) >> 16);  // RNE
}

// ---------------- fused prep: x->bf16 cast  +  W transpose/cast ----------------
__global__ void prep_k(const float* __restrict__ X,
                       const float* __restrict__ Wq, const float* __restrict__ Wk,
                       const float* __restrict__ Wv,
                       unsigned short* __restrict__ XB, unsigned short* __restrict__ WT) {
  __shared__ float t[32][33];
  const int b = blockIdx.x;
  if (b < 4096) {
    const int i = b * 256 + threadIdx.x;
    const f32x4* p = (const f32x4*)X;
    f32x4 a = p[2 * i], c = p[2 * i + 1];
    u16x8 o;
#pragma unroll
    for (int q = 0; q < 4; q++) { o[q] = f2bf(a[q]); o[4 + q] = f2bf(c[q]); }
    *(u16x8*)(XB + (size_t)i * 8) = o;
  } else {
    const int r2 = b - 4096;
    const int seg = r2 >> 10;
    const int rem = r2 & 1023;
    const int k0 = (rem >> 5) * 32, n0 = (rem & 31) * 32;
    const float* W = (seg == 0) ? Wq : (seg == 1) ? Wk : Wv;
    unsigned short* out = WT + (size_t)seg * DM * DM;
    const int tr = threadIdx.x >> 5, tc = threadIdx.x & 31;
#pragma unroll
    for (int p = 0; p < 4; p++) {
      int r = tr + p * 8;
      t[r][tc] = W[(size_t)(k0 + r) * DM + n0 + tc];
    }
    __syncthreads();
#pragma unroll
    for (int p = 0; p < 4; p++) {
      int r = tr + p * 8;
      out[(size_t)(n0 + r) * DM + k0 + tc] = f2bf(t[tc][r]);
    }
  }
}

// softmax-combine: fold 16 tile stats into scale table, TRANSPOSED T[t][idx].
// sv is SPLIT: 32 entries/row (2 wave-halves per tile), folded here.
__global__ void combine_k(const float* __restrict__ ms, const float* __restrict__ ss,
                          float* __restrict__ T) {
  const int idx = blockIdx.x * 256 + threadIdx.x;     // 0..8191
  const float* m = ms + (size_t)idx * 16;
  const float* s = ss + (size_t)idx * 32;
  float mv[16];
#pragma unroll
  for (int t = 0; t < 16; t++) mv[t] = m[t];
  float M = mv[0];
#pragma unroll
  for (int t = 1; t < 16; t++) M = fmaxf(M, mv[t]);
  float L = 0.f;
#pragma unroll
  for (int t = 0; t < 16; t++) L += (s[2 * t] + s[2 * t + 1]) * __expf(mv[t] - M);
  T[idx] = 1.0f;
#pragma unroll
  for (int t = 1; t < 16; t++) T[t * 8192 + idx] = __expf(mv[t - 1] - mv[t]);
  T[16 * 8192 + idx] = __expf(mv[15] - M) / L;
}

// ---------------- bf16 NT GEMM: 128x128 tile, BK=64, reg-staged pipeline ----------------
// K-loop (round-4 proven): buffer_load->VGPR -> MFMA tile k from LDS -> raw
// s_barrier (lgkm only) -> ds_write tile k+1 -> barrier.  XOR swizzle key=row&7.
// XCD-aware 1D grid: bid -> (xcd=bid&7, slot=bid>>3); each XCD owns a private
// rectangular patch of the (batch,M,N) tile grid so same-XCD blocks share
// A-rows/B-panels in that XCD's L2 (workgroup dispatch is XCD round-robin).
// MODE 0: QKV (1536 blocks; xcd patch = 16 M-tiles x 12 N-tiles)
// MODE 1: S-gemm + split-softmax epilogue (1024 blocks; patch = batch-half: 8Mx16N)
// MODE 2: O = telescoped sum (512 blocks; patch = batch-half: 8Mx8N)
template <int MODE, int LDA, int LDB, int KDIM>
__global__ void gemm_nt(const unsigned short* __restrict__ A,
                        const unsigned short* __restrict__ B,
                        void* __restrict__ C0,
                        unsigned short* __restrict__ C1,
                        unsigned short* __restrict__ C2,
                        const float* __restrict__ bq,
                        const float* __restrict__ bk,
                        const float* __restrict__ bv,
                        float* __restrict__ sm,
                        float* __restrict__ sv,
                        const float* __restrict__ Tt) {
  __shared__ unsigned short lbuf[16384];    // 32 KB exactly: lA | lB
  unsigned short* lA = lbuf;
  unsigned short* lB = lbuf + 8192;

  const int tid = threadIdx.x;
  const int w = tid >> 6;
  const int L = tid & 63;
  const int wm = w & 1, wn = w >> 1;
  const int qd = L >> 4, ll = L & 15;

  // ---- XCD-aware tile mapping ----
  const int bid = blockIdx.x;
  const int xcd = bid & 7, slot = bid >> 3;
  int bz, tileM, tileN, nT;
  if (MODE == 0) {
    const int pm = xcd & 3, pn = xcd >> 2;        // 4 M-quarters x 2 N-halves
    const int nloc = slot % 12, mloc = slot / 12; // 192 slots, n-fastest
    bz = 0; tileM = (pm * 16 + mloc) * 128; tileN = (pn * 12 + nloc) * 128; nT = 0;
  } else if (MODE == 1) {
    bz = xcd >> 1;
    const int mh = xcd & 1;
    const int nloc = slot & 15, mloc = slot >> 4; // 128 slots
    tileM = (mh * 8 + mloc) * 128; tileN = nloc * 128; nT = nloc;
  } else {
    bz = xcd >> 1;
    const int mh = xcd & 1;
    const int nloc = slot & 7, mloc = slot >> 3;  // 64 slots
    tileM = (mh * 8 + mloc) * 128; tileN = nloc * 128; nT = nloc;
  }

  const unsigned short* Ab = A;
  const unsigned short* Bb = B;
  if (MODE == 1) { Ab += (size_t)bz * SEQ * DM; Bb += (size_t)bz * SEQ * DM; }
  if (MODE == 2) { Ab += (size_t)bz * SEQ * SEQ; Bb += (size_t)bz * DM * SEQ; }

  // staging geometry: thread t -> row srow=t>>3 (0..31, +32*i), phys chunk t&7,
  // global chunk = (t&7) ^ (row&7).
  const int srow = tid >> 3;
  const int pch = tid & 7;
  const int gch = pch ^ (srow & 7);
  const unsigned short* gA = Ab + (size_t)(tileM + srow) * LDA + gch * 8;
  const unsigned short* gB = Bb + (size_t)(tileN + srow) * LDB + gch * 8;
  unsigned short* wA = &lA[srow * 64 + pch * 8];
  unsigned short* wB = &lB[srow * 64 + pch * 8];

  u16x8 rA[4], rB[4];
#define LOADT(kt) do {                                                         \
    const size_t kk_ = (size_t)(kt) * 64;                                      \
    _Pragma("unroll")                                                          \
    for (int i_ = 0; i_ < 4; i_++) {                                           \
      rA[i_] = *(const u16x8*)(gA + (size_t)i_ * 32 * LDA + kk_);              \
      rB[i_] = *(const u16x8*)(gB + (size_t)i_ * 32 * LDB + kk_);              \
    }                                                                          \
  } while (0)
#define WRITET() do {                                                          \
    _Pragma("unroll")                                                          \
    for (int i_ = 0; i_ < 4; i_++) {                                           \
      *(u16x8*)(wA + i_ * 32 * 64) = rA[i_];                                   \
      *(u16x8*)(wB + i_ * 32 * 64) = rB[i_];                                   \
    }                                                                          \
  } while (0)

  f32x4 acc[4][4];
#pragma unroll
  for (int i = 0; i < 4; i++)
#pragma unroll
    for (int j = 0; j < 4; j++) acc[i][j] = (f32x4){0.f, 0.f, 0.f, 0.f};

  const int sw = L & 7;         // swizzle key for fragment rows

  // MODE2: prefetched scale-table values (broadcast-coalesced layout)
  float tTn[4][4];
  const float* Tb = nullptr;
  if (MODE == 2) {
    Tb = Tt + (size_t)bz * SEQ + tileM + wm * 64;
#pragma unroll
    for (int i = 0; i < 4; i++)
#pragma unroll
      for (int r = 0; r < 4; r++) tTn[i][r] = Tb[1 * 8192 + i * 16 + qd * 4 + r];
  }

  constexpr int NK = KDIM / 64;
  LOADT(0);
  WRITET();                      // vmcnt wait inserted before these writes
  __syncthreads();

  for (int k = 0; k < NK; ++k) {
    if (MODE == 2 && k >= 2 && (k & 1) == 0) {
#pragma unroll
      for (int i = 0; i < 4; i++)
#pragma unroll
        for (int j = 0; j < 4; j++)
#pragma unroll
          for (int r = 0; r < 4; r++) acc[i][j][r] *= tTn[i][r];
      const int tn = (k >> 1) + 1;
#pragma unroll
      for (int i = 0; i < 4; i++)
#pragma unroll
        for (int r = 0; r < 4; r++) tTn[i][r] = Tb[(size_t)tn * 8192 + i * 16 + qd * 4 + r];
    }

    if (k + 1 < NK) LOADT(k + 1);     // global->VGPR, flies across compute

#pragma unroll
    for (int s = 0; s < 2; s++) {     // two K=32 halves of the BK=64 tile
      const int pc = ((s * 4 + qd) ^ sw) * 8;
      s16x8 av[4], bv4[4];
#pragma unroll
      for (int i = 0; i < 4; i++)
        av[i] = *(const s16x8*)&lA[(wm * 64 + i * 16 + ll) * 64 + pc];
#pragma unroll
      for (int j = 0; j < 4; j++)
        bv4[j] = *(const s16x8*)&lB[(wn * 64 + j * 16 + ll) * 64 + pc];
#pragma unroll
      for (int i = 0; i < 4; i++)
#pragma unroll
        for (int j = 0; j < 4; j++)
          acc[i][j] = __builtin_amdgcn_mfma_f32_16x16x32_bf16(av[i], bv4[j], acc[i][j], 0, 0, 0);
    }

    if (k + 1 < NK) {
      __builtin_amdgcn_s_waitcnt(0xC07F);       // lgkmcnt(0) only; vmem in flight
      __builtin_amdgcn_sched_barrier(0);
      __builtin_amdgcn_s_barrier();
      __builtin_amdgcn_sched_barrier(0);
      WRITET();                                  // vmcnt wait auto-inserted here
      __syncthreads();
    }
  }
#undef LOADT
#undef WRITET

  // ---------------- epilogues ----------------
  // C/D layout: col = wn*64 + j*16 + ll ; row = wm*64 + i*16 + qd*4 + r (local)
  if (MODE == 0) {
#pragma unroll
    for (int i = 0; i < 4; i++) {
      const int gm0 = tileM + wm * 64 + i * 16 + qd * 4;
#pragma unroll
      for (int j = 0; j < 4; j++) {
        const int gn = tileN + wn * 64 + j * 16 + ll;
        const int seg = gn >> 10;          // block-uniform
        const int colin = gn & 1023;
        if (seg == 0) {
          const float bias = bq[colin];
          unsigned short* Q = (unsigned short*)C0;
#pragma unroll
          for (int r = 0; r < 4; r++) Q[(size_t)(gm0 + r) * DM + colin] = f2bf(acc[i][j][r] + bias);
        } else if (seg == 1) {
          const float bias = bk[colin];
#pragma unroll
          for (int r = 0; r < 4; r++) C1[(size_t)(gm0 + r) * DM + colin] = f2bf(acc[i][j][r] + bias);
        } else {                            // V, stored transposed: Vt[b][d][s]
          const float bias = bv[colin];
          u16x4 pk;
#pragma unroll
          for (int r = 0; r < 4; r++) pk[r] = f2bf(acc[i][j][r] + bias);
          const int b = gm0 >> 11, s0 = gm0 & 2047;
          *(u16x4*)(C2 + ((size_t)((b << 10) + colin)) * SEQ + s0) = pk;
        }
      }
    }
  } else if (MODE == 1) {
    __syncthreads();                       // all waves done with K-loop LDS
    // scale by 1/32; per-wave (64-col) row max via shfl
    float mt[4][4];
#pragma unroll
    for (int i = 0; i < 4; i++)
#pragma unroll
      for (int r = 0; r < 4; r++) {
#pragma unroll
        for (int j = 0; j < 4; j++) acc[i][j][r] *= 0.03125f;
        float v = fmaxf(fmaxf(acc[i][0][r], acc[i][1][r]), fmaxf(acc[i][2][r], acc[i][3][r]));
#pragma unroll
        for (int m = 1; m < 16; m <<= 1) v = fmaxf(v, __shfl_xor(v, m, 16));
        mt[i][r] = v;
      }
    // cross-wave max exchange through (free) lbuf head — consumed before P' writes
    float* fred = (float*)lbuf;            // 256 floats
    if (ll == 0) {
#pragma unroll
      for (int i = 0; i < 4; i++)
#pragma unroll
        for (int r = 0; r < 4; r++)
          fred[wn * 128 + wm * 64 + i * 16 + qd * 4 + r] = mt[i][r];
    }
    __syncthreads();
#pragma unroll
    for (int i = 0; i < 4; i++)
#pragma unroll
      for (int r = 0; r < 4; r++) {
        const int row = wm * 64 + i * 16 + qd * 4 + r;
        mt[i][r] = fmaxf(fred[row], fred[128 + row]);
      }
    __syncthreads();                       // mt in regs; lbuf now free for P'
    // exp; P' bf16 into lbuf (swizzled); per-wave partial sums straight to sv
#pragma unroll
    for (int i = 0; i < 4; i++)
#pragma unroll
      for (int r = 0; r < 4; r++) {
        const int row = wm * 64 + i * 16 + qd * 4 + r;
        float s = 0.f;
#pragma unroll
        for (int j = 0; j < 4; j++) {
          float e = __expf(acc[i][j][r] - mt[i][r]);
          s += e;
          const int col = wn * 64 + j * 16 + ll;
          lbuf[row * 128 + ((((col >> 4) ^ (row & 7)) << 4) | (col & 15))] = f2bf(e);
        }
#pragma unroll
        for (int m = 1; m < 16; m <<= 1) s += __shfl_xor(s, m, 16);
        if (ll == 0) {
          const size_t base = (size_t)bz * SEQ + tileM + row;
          sv[base * 32 + nT * 2 + wn] = s;
          if (wn == 0) sm[base * 16 + nT] = mt[i][r];
        }
      }
    __syncthreads();                       // lbuf complete
    // coalesced P' store: 8 x u16x8 per thread
    unsigned short* P = (unsigned short*)C0 + (size_t)bz * SEQ * SEQ;
#pragma unroll
    for (int p = 0; p < 8; p++) {
      const int c = p * 256 + tid;
      const int row = c >> 4, cg = c & 15;
      const int phys = ((((cg >> 1) ^ (row & 7)) << 4) | ((cg & 1) << 3));
      u16x8 val = *(const u16x8*)&lbuf[row * 128 + phys];
      *(u16x8*)(P + (size_t)(tileM + row) * SEQ + tileN + cg * 8) = val;
    }
  } else {
    // final scale T[16] (in tTn), store fp32
    float* O = (float*)C0 + (size_t)bz * SEQ * DM;
#pragma unroll
    for (int i = 0; i < 4; i++) {
      const int gm0 = tileM + wm * 64 + i * 16 + qd * 4;
#pragma unroll
      for (int j = 0; j < 4; j++) {
        const int gn = tileN + wn * 64 + j * 16 + ll;
#pragma unroll
        for (int r = 0; r < 4; r++)
          O[(size_t)(gm0 + r) * DM + gn] = acc[i][j][r] * tTn[i][r];
      }
    }
  }
}

// ---------------- launch ----------------
// ws layout (bytes):
//   xb  @ 0         : 16 MB   bf16 x       [8192,1024]
//   wt  @ 16777216  :  6 MB   bf16 W^T     [3072,1024]
//   qb  @ 23068672  : 16 MB   bf16 Q       [8192,1024]
//   kb  @ 39845888  : 16 MB   bf16 K       [8192,1024]
//   vt  @ 56623104  : 16 MB   bf16 V^T     [4][1024][2048]
//   P   @ 73400320  : 32 MB   bf16 P'      [4][2048][2048]
//   ms  @ 106954752 : 512 KB  fp32 stats m [4][2048][16]
//   ss  @ 107479040 : 1 MB    fp32 stats s [4][2048][32]  (split per wave-half)
//   T   @ 108527616 : 544 KB  fp32 scale   [17][4*2048]   (transposed)
// total ~109 MB
extern "C" void kernel_launch(void* const* d_in, const int* in_sizes, int n_in,
                              void* d_out, int out_size, void* d_ws, size_t ws_size,
                              hipStream_t stream) {
  (void)in_sizes; (void)n_in; (void)out_size; (void)ws_size;
  const float* x  = (const float*)d_in[0];
  const float* Wq = (const float*)d_in[1];
  const float* bq = (const float*)d_in[2];
  const float* Wk = (const float*)d_in[3];
  const float* bk = (const float*)d_in[4];
  const float* Wv = (const float*)d_in[5];
  const float* bv = (const float*)d_in[6];
  float* out = (float*)d_out;
  char* ws = (char*)d_ws;
  unsigned short* xb = (unsigned short*)(ws + 0);
  unsigned short* wt = (unsigned short*)(ws + 16777216);
  unsigned short* qb = (unsigned short*)(ws + 23068672);
  unsigned short* kb = (unsigned short*)(ws + 39845888);
  unsigned short* vt = (unsigned short*)(ws + 56623104);
  unsigned short* P  = (unsigned short*)(ws + 73400320);
  float*          ms = (float*)(ws + 106954752);
  float*          ss = (float*)(ws + 107479040);
  float*          Tt = (float*)(ws + 108527616);

  prep_k<<<7168, 256, 0, stream>>>(x, Wq, Wk, Wv, xb, wt);
  gemm_nt<0, 1024, 1024, 1024><<<1536, 256, 0, stream>>>(
      xb, wt, (void*)qb, kb, vt, bq, bk, bv, nullptr, nullptr, nullptr);
  gemm_nt<1, 1024, 1024, 1024><<<1024, 256, 0, stream>>>(
      qb, kb, (void*)P, nullptr, nullptr, nullptr, nullptr, nullptr, ms, ss, nullptr);
  combine_k<<<32, 256, 0, stream>>>(ms, ss, Tt);
  gemm_nt<2, 2048, 2048, 2048><<<512, 256, 0, stream>>>(
      P, vt, (void*)out, nullptr, nullptr, nullptr, nullptr, nullptr, nullptr, nullptr, Tt);
}